// Round 9
// baseline (174.082 us; speedup 1.0000x reference)
//
#include <hip/hip_runtime.h>
#include <math.h>

#define B 8
#define IMH 512
#define IMW 512
#define HW (IMH*IMW)
#define NBINS 256

// pyramid per-image: levels 1..4 (256^2, 128^2, 64^2, 32^2)
#define PYR_PER_IMG (65536 + 16384 + 4096 + 1024)   // 87040
#define PYR_OFF_L1 0
#define PYR_OFF_L2 65536
#define PYR_OFF_L3 81920
#define PYR_OFF_L4 86016

// workspace float-index offsets
#define OFF_PPYR 0
#define OFF_TPYR (B*PYR_PER_IMG)
#define OFF_HISTPART (2*B*PYR_PER_IMG)              // u32: B*256*768 (u16-packed bins)
#define OFF_LABPART  (OFF_HISTPART + B*256*768)     // float: 2048
#define OFF_ACC      (OFF_LABPART + 2048)           // byte offset % 8 == 0
// doubles: sAcc[40], cAcc[40], histL1acc[8], labSumD[1], counter[1 slot] = 90

typedef float f2 __attribute__((ext_vector_type(2)));

__device__ __forceinline__ f2 mkf2(float a, float b) { f2 r; r.x = a; r.y = b; return r; }
__device__ __forceinline__ f2 shfl_down_f2(f2 v, int d) {
    return mkf2(__shfl_down(v.x, d, 64), __shfl_down(v.y, d, 64));
}
__device__ __forceinline__ f2 shfl_f2(f2 v, int src) {
    return mkf2(__shfl(v.x, src, 64), __shfl(v.y, src, 64));
}
__device__ __forceinline__ f2 clamp01_f2(f2 a) {
    a.x = fminf(fmaxf(a.x, 0.0f), 1.0f);
    a.y = fminf(fmaxf(a.y, 0.0f), 1.0f);
    return a;
}

// native exp2/log2 (v_exp_f32 / v_log_f32, <=1 ulp). x must be > 0.
__device__ __forceinline__ float fastpow(float x, float y) {
    return __builtin_amdgcn_exp2f(y * __builtin_amdgcn_logf(x));
}

// packed rgb2lab: component .x = pred, .y = tgt.
__device__ __forceinline__ void rgb2lab_pk(f2 r, f2 g, f2 b, f2 lab[3]) {
    f2 v[3] = {r, g, b};
    f2 lin[3];
    #pragma unroll
    for (int c = 0; c < 3; ++c) {
        f2 x = v[c];
        float hx = fastpow((fmaxf(x.x, 1e-4f) + 0.055f) * (float)(1.0/1.055), 2.4f);
        float hy = fastpow((fmaxf(x.y, 1e-4f) + 0.055f) * (float)(1.0/1.055), 2.4f);
        lin[c].x = (x.x <= 0.04045f) ? x.x * (float)(1.0/12.92) : hx;
        lin[c].y = (x.y <= 0.04045f) ? x.y * (float)(1.0/12.92) : hy;
    }
    f2 X = 0.412453f*lin[0] + 0.357580f*lin[1] + 0.180423f*lin[2];
    f2 Y = 0.212671f*lin[0] + 0.715160f*lin[1] + 0.072169f*lin[2];
    f2 Z = 0.019334f*lin[0] + 0.119193f*lin[1] + 0.950227f*lin[2];
    X = X * (float)(1.0/0.950456);
    Z = Z * (float)(1.0/1.088754);
    const float eps3   = (float)((6.0/29.0)*(6.0/29.0)*(6.0/29.0));
    const float rd3e2  = (float)(1.0/(3.0*(6.0/29.0)*(6.0/29.0)));
    const float c429   = (float)(4.0/29.0);
    f2 xyz[3] = {X, Y, Z};
    f2 f[3];
    #pragma unroll
    for (int c = 0; c < 3; ++c) {
        float ax = xyz[c].x, ay = xyz[c].y;
        f[c].x = (ax <= eps3) ? (ax * rd3e2 + c429) : fastpow(fmaxf(ax, 1e-4f), (float)(1.0/3.0));
        f[c].y = (ay <= eps3) ? (ay * rd3e2 + c429) : fastpow(fmaxf(ay, 1e-4f), (float)(1.0/3.0));
    }
    f2 L  = 116.0f*f[1] - 16.0f;
    f2 A  = 500.0f*f[0] - 500.0f*f[1];
    f2 Bc = 200.0f*f[1] - 200.0f*f[2];
    lab[0] = L * 0.01f;
    lab[1] = (A * (float)(1.0/110.0) + 1.0f) * 0.5f;
    lab[2] = (Bc * (float)(1.0/110.0) + 1.0f) * 0.5f;
}

#define TST 37   // LDS row stride for 36-wide tiles

// packed separable 5x5 Gaussian SSIM over a 36x36 f2 tile ({pred,tgt} interleaved).
__device__ __forceinline__ void conv_ssim(const f2* tile, int t, float& ssum, float& csum) {
    double gd[5]; double gs = 0.0;
    #pragma unroll
    for (int i = 0; i < 5; ++i) { gd[i] = exp(-(double)((i-2)*(i-2)) / 4.5); gs += gd[i]; }
    float gw[5];
    #pragma unroll
    for (int i = 0; i < 5; ++i) gw[i] = (float)(gd[i] / gs);

    int lx = t & 31;
    int yg = t >> 5;

    f2 rA[8], rB[8];     // {m1,m2}, {m11,m22}
    float r12[8];
    #pragma unroll
    for (int k = 0; k < 8; ++k) {
        int row = yg * 4 + k;
        const f2* p = &tile[row * TST + lx];
        f2 sA = {0.f, 0.f}, sB = {0.f, 0.f};
        float s12 = 0.f;
        #pragma unroll
        for (int dx = 0; dx < 5; ++dx) {
            f2 av = p[dx];
            float wv = gw[dx];
            sA += wv * av;
            f2 sq = av * av;
            sB += wv * sq;
            s12 = fmaf(wv, av.x * av.y, s12);
        }
        rA[k] = sA; rB[k] = sB; r12[k] = s12;
    }

    const float C1 = (float)(0.01 * 0.01);
    const float C2 = (float)(0.03 * 0.03);
    ssum = 0.f; csum = 0.f;
    #pragma unroll
    for (int j = 0; j < 4; ++j) {
        f2 mA = {0.f, 0.f}, mB = {0.f, 0.f};
        float m12 = 0.f;
        #pragma unroll
        for (int k = 0; k < 5; ++k) {
            float wv = gw[k];
            mA += wv * rA[j + k];
            mB += wv * rB[j + k];
            m12 = fmaf(wv, r12[j + k], m12);
        }
        float m1 = mA.x, m2 = mA.y;
        float v1  = mB.x - m1 * m1;
        float v2  = mB.y - m2 * m2;
        float v12 = m12 - m1 * m2;
        float den2 = v1 + v2 + C2;
        ssum += ((2.0f*m1*m2 + C1) * (2.0f*v12 + C2)) / ((m1*m1 + m2*m2 + C1) * den2);
        csum += (2.0f*v12 + C2) / den2;
    }
}

__device__ __forceinline__ void halo_coords(int h, int& hr, int& hc) {
    if (h < 72)       { hr = h / 36;            hc = h % 36; }
    else if (h < 144) { int u = h - 72;  hr = 34 + u / 36; hc = u % 36; }
    else              { int u = h - 144; hr = 2 + (u >> 2); int q = u & 3; hc = (q < 2) ? q : 32 + q; }
}

// Fused: LAB + hist partial + lvl0 SSIM (halo recompute, prefetched) + full pyramid.
// One block = one 32x32 tile. grid (256, B) x 256; 4 px/thread.
__global__ void lab_ssim0_kernel(const float* __restrict__ pred,
                                 const float* __restrict__ tgt,
                                 unsigned* __restrict__ histPart,
                                 float* __restrict__ labPart,
                                 double* __restrict__ accs,
                                 float* __restrict__ ppyr,
                                 float* __restrict__ tpyr) {
    __shared__ f2 ls[36 * TST];          // packed {Lp, Lt} halo tile
    __shared__ unsigned lhist[6 * NBINS];
    __shared__ f2 s1[16 * 16];           // packed L1
    __shared__ float red12[12];

    int t  = threadIdx.x;
    int b  = blockIdx.y;
    int bx = blockIdx.x;

    for (int i = t; i < 6 * NBINS; i += 256) lhist[i] = 0;
    __syncthreads();                                            // B1

    // XCD-aware swizzle: consecutive dispatch ids -> disjoint 2-tile-row strips
    int tile = ((bx & 7) << 5) | (bx >> 3);
    int tx0 = (tile & 15) << 5;
    int ty0 = (tile >> 4) << 5;
    int r   = t >> 3;            // row within tile (0..31)
    int c4  = (t & 7) << 2;      // col within tile (0,4,..,28)
    int gy  = ty0 + r;

    const float* pimg = pred + (size_t)b * 3 * HW;
    const float* timg = tgt  + (size_t)b * 3 * HW;
    size_t ibase = (size_t)gy * IMW + tx0 + c4;

    // ---- issue ALL loads up front (interior 6x float4 + halo px t's 6 scalars) ----
    float prA[4], pgA[4], pbA[4], trA[4], tgA[4], tbA[4];
    *(float4*)&prA[0] = *(const float4*)(pimg + ibase);
    *(float4*)&pgA[0] = *(const float4*)(pimg + ibase + HW);
    *(float4*)&pbA[0] = *(const float4*)(pimg + ibase + 2*HW);
    *(float4*)&trA[0] = *(const float4*)(timg + ibase);
    *(float4*)&tgA[0] = *(const float4*)(timg + ibase + HW);
    *(float4*)&tbA[0] = *(const float4*)(timg + ibase + 2*HW);

    int hr0, hc0;
    halo_coords(t, hr0, hc0);
    int hy0 = ty0 - 2 + hr0;
    int hx0 = tx0 - 2 + hc0;
    bool hv0 = ((unsigned)hy0 < 512u) && ((unsigned)hx0 < 512u);
    size_t ho = hv0 ? ((size_t)hy0 * IMW + hx0) : 0;   // clamped addr, masked later
    float h_pr = pimg[ho], h_pg = pimg[ho + HW], h_pb = pimg[ho + 2*HW];
    float h_tr = timg[ho], h_tg = timg[ho + HW], h_tb = timg[ho + 2*HW];

    // ---- interior compute (halo loads in flight) ----
    float l1 = 0.0f;
    f2 pL[4];
    #pragma unroll
    for (int k = 0; k < 4; ++k) {
        f2 lab[3];
        rgb2lab_pk(mkf2(prA[k], trA[k]), mkf2(pgA[k], tgA[k]), mkf2(pbA[k], tbA[k]), lab);
        #pragma unroll
        for (int c = 0; c < 3; ++c) {
            f2 lc = clamp01_f2(lab[c]);
            l1 += fabsf(lc.x - lc.y);
            int ip = min(max((int)floorf(lc.x * (float)NBINS), 0), NBINS - 1);
            int it = min(max((int)floorf(lc.y * (float)NBINS), 0), NBINS - 1);
            atomicAdd(&lhist[c * NBINS + ip], 1u);
            atomicAdd(&lhist[(3 + c) * NBINS + it], 1u);
            if (c == 0) pL[k] = lc;
        }
        ls[(r + 2) * TST + (c4 + 2 + k)] = pL[k];
    }

    // ---- halo px t (prefetched) ----
    {
        f2 lab[3];
        rgb2lab_pk(mkf2(h_pr, h_tr), mkf2(h_pg, h_tg), mkf2(h_pb, h_tb), lab);
        f2 Lv = hv0 ? clamp01_f2(lab[0]) : mkf2(0.f, 0.f);
        ls[hr0 * TST + hc0] = Lv;
    }
    // ---- remaining 16 halo px (t < 16) ----
    if (t < 16) {
        int hr, hc;
        halo_coords(256 + t, hr, hc);
        int hy = ty0 - 2 + hr;
        int hx = tx0 - 2 + hc;
        f2 Lv = {0.f, 0.f};
        if ((unsigned)hy < 512u && (unsigned)hx < 512u) {
            size_t o = (size_t)hy * IMW + hx;
            f2 lab[3];
            rgb2lab_pk(mkf2(pimg[o], timg[o]),
                       mkf2(pimg[o + HW], timg[o + HW]),
                       mkf2(pimg[o + 2*HW], timg[o + 2*HW]), lab);
            Lv = clamp01_f2(lab[0]);
        }
        ls[hr * TST + hc] = Lv;
    }
    __syncthreads();                                            // B2

    // non-atomic per-block histogram partial, u16-packed two bins per u32
    unsigned* hp = histPart + ((size_t)b * 256 + bx) * 768;
    for (int i = t; i < 768; i += 256)
        hp[i] = (lhist[2*i] & 0xFFFFu) | (lhist[2*i + 1] << 16);

    // pyramid L1 from registers (shuffles), packed
    float* pyrP = ppyr + (size_t)b * PYR_PER_IMG;
    float* pyrT = tpyr + (size_t)b * PYR_PER_IMG;
    f2 ph0 = pL[0] + pL[1], ph1 = pL[2] + pL[3];
    f2 ph0b = shfl_down_f2(ph0, 8);
    f2 ph1b = shfl_down_f2(ph1, 8);
    if ((t & 8) == 0) {                 // even row r
        int y1 = r >> 1;
        int x1 = (t & 7) << 1;
        f2 v0 = 0.25f * (ph0 + ph0b);
        f2 v1 = 0.25f * (ph1 + ph1b);
        s1[y1 * 16 + x1]     = v0;
        s1[y1 * 16 + x1 + 1] = v1;
        int g1 = ((ty0 >> 1) + y1) * 256 + (tx0 >> 1) + x1;
        *(float2*)&pyrP[PYR_OFF_L1 + g1] = make_float2(v0.x, v1.x);
        *(float2*)&pyrT[PYR_OFF_L1 + g1] = make_float2(v0.y, v1.y);
    }
    __syncthreads();                                            // B3

    // lvl0 SSIM from packed LDS tile
    float ssum, csum;
    conv_ssim(ls, t, ssum, csum);

    // pyramid L2-L4: wave 0 only (shuffle cascade, no barriers)
    if (t < 64) {
        int y2 = t >> 3, x2 = t & 7;
        const f2* s = &s1[(2*y2) * 16 + 2*x2];
        f2 v2 = 0.25f * (s[0] + s[1] + s[16] + s[17]);
        pyrP[PYR_OFF_L2 + ((ty0 >> 2) + y2) * 128 + (tx0 >> 2) + x2] = v2.x;
        pyrT[PYR_OFF_L2 + ((ty0 >> 2) + y2) * 128 + (tx0 >> 2) + x2] = v2.y;

        int y3 = (t >> 2) & 3, x3 = t & 3;
        f2 v3 = 0.25f * (shfl_f2(v2, (2*y3)*8 + 2*x3)     + shfl_f2(v2, (2*y3)*8 + 2*x3 + 1) +
                         shfl_f2(v2, (2*y3+1)*8 + 2*x3)   + shfl_f2(v2, (2*y3+1)*8 + 2*x3 + 1));
        if (t < 16) {
            pyrP[PYR_OFF_L3 + ((ty0 >> 3) + y3) * 64 + (tx0 >> 3) + x3] = v3.x;
            pyrT[PYR_OFF_L3 + ((ty0 >> 3) + y3) * 64 + (tx0 >> 3) + x3] = v3.y;
        }
        int y4 = (t >> 1) & 1, x4 = t & 1;
        f2 v4 = 0.25f * (shfl_f2(v3, (2*y4)*4 + 2*x4)     + shfl_f2(v3, (2*y4)*4 + 2*x4 + 1) +
                         shfl_f2(v3, (2*y4+1)*4 + 2*x4)   + shfl_f2(v3, (2*y4+1)*4 + 2*x4 + 1));
        if (t < 4) {
            pyrP[PYR_OFF_L4 + ((ty0 >> 4) + y4) * 32 + (tx0 >> 4) + x4] = v4.x;
            pyrT[PYR_OFF_L4 + ((ty0 >> 4) + y4) * 32 + (tx0 >> 4) + x4] = v4.y;
        }
    }

    // single combined reduction: l1, ssum, csum
    int lane = t & 63;
    int wid  = t >> 6;
    #pragma unroll
    for (int o = 32; o >= 1; o >>= 1) {
        l1   += __shfl_down(l1, o, 64);
        ssum += __shfl_down(ssum, o, 64);
        csum += __shfl_down(csum, o, 64);
    }
    if (lane == 0) {
        red12[wid * 3 + 0] = l1;
        red12[wid * 3 + 1] = ssum;
        red12[wid * 3 + 2] = csum;
    }
    __syncthreads();                                            // B4
    if (t < 4) {
        float a0 = red12[t * 3 + 0];
        float a1 = red12[t * 3 + 1];
        float a2 = red12[t * 3 + 2];
        #pragma unroll
        for (int o = 2; o >= 1; o >>= 1) {
            a0 += __shfl_down(a0, o, 64);
            a1 += __shfl_down(a1, o, 64);
            a2 += __shfl_down(a2, o, 64);
        }
        if (t == 0) {
            labPart[b * 256 + bx] = a0;
            atomicAdd(&accs[b * 5 + 0], (double)a1);        // sAcc lvl0
            atomicAdd(&accs[40 + b * 5 + 0], (double)a2);   // cAcc lvl0
        }
    }
}

// Merged tail: 693 blocks.
//   bx < 680           : SSIM levels 1-4 (85 per image)
//   680 <= bx < 692    : hist partial reduce, COALESCED (thread owns one packed
//                        word, loops over 256 tiles; lanes contiguous in memory;
//                        image boundary = 384 words aligns to wave boundary)
//   bx == 692          : labPart reduce
// Last finishing block computes the final outputs.
__global__ void tail_kernel(const float* __restrict__ ppyr,
                            const float* __restrict__ tpyr,
                            const unsigned* __restrict__ histPart,
                            const float* __restrict__ labPart,
                            double* __restrict__ accs,
                            float* __restrict__ out) {
    __shared__ f2 tls[36 * TST];
    __shared__ float red12[12];
    int t = threadIdx.x;
    int bx = blockIdx.x;
    double* histL1acc = accs + 80;
    double* labSumD   = accs + 88;
    unsigned* counter = (unsigned*)(accs + 89);

    if (bx < 680) {
        int b = bx / 85;
        int sub = bx - b * 85;
        int lvl, pblk;
        if (sub < 64)      { lvl = 1; pblk = sub; }
        else if (sub < 80) { lvl = 2; pblk = sub - 64; }
        else if (sub < 84) { lvl = 3; pblk = sub - 80; }
        else               { lvl = 4; pblk = 0; }

        const int offs[5] = {0, PYR_OFF_L1, PYR_OFF_L2, PYR_OFF_L3, PYR_OFF_L4};
        int w = 512 >> lvl;
        const float* i1 = ppyr + (size_t)b * PYR_PER_IMG + offs[lvl];
        const float* i2 = tpyr + (size_t)b * PYR_PER_IMG + offs[lvl];

        int tprShift = 4 - lvl;
        int ty0 = (pblk >> tprShift) << 5;
        int tx0 = (pblk & ((1 << tprShift) - 1)) << 5;

        for (int i = t; i < 36 * 36; i += 256) {
            int r = i / 36, c = i % 36;
            int gy = ty0 - 2 + r;
            int gx = tx0 - 2 + c;
            bool ok = ((unsigned)gy < (unsigned)w) && ((unsigned)gx < (unsigned)w);
            int gi = gy * w + gx;
            tls[r * TST + c] = ok ? mkf2(i1[gi], i2[gi]) : mkf2(0.f, 0.f);
        }
        __syncthreads();

        float ssum, csum;
        conv_ssim(tls, t, ssum, csum);

        int lane = t & 63;
        int wid  = t >> 6;
        #pragma unroll
        for (int o = 32; o >= 1; o >>= 1) {
            ssum += __shfl_down(ssum, o, 64);
            csum += __shfl_down(csum, o, 64);
        }
        if (lane == 0) {
            red12[wid * 3 + 0] = ssum;
            red12[wid * 3 + 1] = csum;
        }
        __syncthreads();
        if (t < 4) {
            float a1 = red12[t * 3 + 0];
            float a2 = red12[t * 3 + 1];
            #pragma unroll
            for (int o = 2; o >= 1; o >>= 1) {
                a1 += __shfl_down(a1, o, 64);
                a2 += __shfl_down(a2, o, 64);
            }
            if (t == 0) {
                atomicAdd(&accs[b * 5 + lvl], (double)a1);
                atomicAdd(&accs[40 + b * 5 + lvl], (double)a2);
            }
        }
    } else if (bx < 692) {
        // coalesced hist reduce: global word id g in [0, 8*384)
        int g = (bx - 680) * 256 + t;
        int b = g / 384;              // image (wave-uniform: 384 % 64 == 0)
        int w = g - b * 384;          // packed word within image (bins 2w, 2w+1)
        const unsigned* p = histPart + (size_t)b * 256 * 768;
        unsigned sPlo = 0, sPhi = 0, sTlo = 0, sThi = 0;
        #pragma unroll 4
        for (int i = 0; i < 256; ++i) {
            unsigned wP = p[(size_t)i * 768 + w];          // lanes contiguous
            unsigned wT = p[(size_t)i * 768 + 384 + w];
            sPlo += wP & 0xFFFFu;  sPhi += wP >> 16;
            sTlo += wT & 0xFFFFu;  sThi += wT >> 16;
        }
        float val = fabsf((float)((int)sPlo - (int)sTlo)) +
                    fabsf((float)((int)sPhi - (int)sThi));   // exact: sums < 2^24
        // per-wave reduce (each wave is one image) + one atomic per wave
        #pragma unroll
        for (int o = 32; o >= 1; o >>= 1) val += __shfl_down(val, o, 64);
        if ((t & 63) == 0) atomicAdd(&histL1acc[b], (double)val);
        __syncthreads();   // keep barrier count uniform-ish (block-local)
    } else {
        float s = 0.0f;
        #pragma unroll
        for (int k = 0; k < 8; ++k) s += labPart[t + k * 256];
        int lane = t & 63;
        int wid  = t >> 6;
        #pragma unroll
        for (int o = 32; o >= 1; o >>= 1) s += __shfl_down(s, o, 64);
        if (lane == 0) red12[wid * 3] = s;
        __syncthreads();
        if (t == 0) labSumD[0] = (double)(red12[0] + red12[3] + red12[6] + red12[9]);
    }

    __syncthreads();
    if (t == 0) {
        __threadfence();
        unsigned old = atomicAdd(counter, 1u);
        if (old == 692u) {            // last of 693 blocks
            __threadfence();
            volatile double* vacc = accs;
            float hist_loss = 0.0f;
            for (int b = 0; b < B; ++b) {
                float l1 = (float)(vacc[80 + b] / (double)(3 * NBINS));
                float wgt = exp2f((float)(b - B));   // 2^(b - n), n = B = 8
                hist_loss += wgt * (l1 + 1.0f);
            }
            float scaler = (float)HW / 20.0f;
            hist_loss = hist_loss / (float)B / scaler;
            float lab_l1 = (float)(vacc[88] / (double)((size_t)B * 3 * HW));
            out[0] = lab_l1 + hist_loss;

            const float msw[5] = {0.0448f, 0.2856f, 0.3001f, 0.2363f, 0.1333f};
            const int npix[5] = {HW, HW/4, HW/16, HW/64, HW/256};
            float loss = 0.0f;
            for (int b = 0; b < B; ++b) {
                float ms = 1.0f;
                for (int l = 0; l < 4; ++l) {
                    float cs = (float)(vacc[40 + b * 5 + l] / (double)npix[l]);
                    float csn = (cs + 1.0f) / 2.0f;
                    ms *= powf(csn, msw[l]);
                }
                float sm = (float)(vacc[b * 5 + 4] / (double)npix[4]);
                float smn = (sm + 1.0f) / 2.0f;
                ms *= powf(smn, msw[4]);
                loss += 1.0f - ms;
            }
            out[1] = loss / (float)B;
        }
    }
}

extern "C" void kernel_launch(void* const* d_in, const int* in_sizes, int n_in,
                              void* d_out, int out_size, void* d_ws, size_t ws_size,
                              hipStream_t stream) {
    const float* pred = (const float*)d_in[1];
    const float* tgt  = (const float*)d_in[2];
    float* ws_f = (float*)d_ws;

    float* ppyr  = ws_f + OFF_PPYR;
    float* tpyr  = ws_f + OFF_TPYR;
    unsigned* histPart = (unsigned*)(ws_f + OFF_HISTPART);
    float* labPart = ws_f + OFF_LABPART;
    double* accs = (double*)(ws_f + OFF_ACC);
    float* out = (float*)d_out;

    // zero accumulators + completion counter (90 doubles)
    hipMemsetAsync(accs, 0, 90 * sizeof(double), stream);

    lab_ssim0_kernel<<<dim3(256, B), 256, 0, stream>>>(pred, tgt, histPart, labPart,
                                                       accs, ppyr, tpyr);

    tail_kernel<<<693, 256, 0, stream>>>(ppyr, tpyr, histPart, labPart, accs, out);
}

// Round 10
// 164.316 us; speedup vs baseline: 1.0594x; 1.0594x over previous
//
#include <hip/hip_runtime.h>
#include <math.h>

#define B 8
#define IMH 512
#define IMW 512
#define HW (IMH*IMW)
#define NBINS 256

// pyramid per-image: levels 1..4 (256^2, 128^2, 64^2, 32^2)
#define PYR_PER_IMG (65536 + 16384 + 4096 + 1024)   // 87040
#define PYR_OFF_L1 0
#define PYR_OFF_L2 65536
#define PYR_OFF_L3 81920
#define PYR_OFF_L4 86016

// workspace float-index offsets
#define OFF_PPYR 0
#define OFF_TPYR (B*PYR_PER_IMG)
#define OFF_HISTPART (2*B*PYR_PER_IMG)              // u32: B*256*768 (u16-packed bins)
#define OFF_LABPART  (OFF_HISTPART + B*256*768)     // float: 2048
#define OFF_ACC      (OFF_LABPART + 2048)           // byte offset % 8 == 0
// doubles: sAcc[40], cAcc[40], histL1acc[8], labSumD[1], counter[1 slot] = 90

typedef float f2 __attribute__((ext_vector_type(2)));

__device__ __forceinline__ f2 mkf2(float a, float b) { f2 r; r.x = a; r.y = b; return r; }
__device__ __forceinline__ f2 shfl_down_f2(f2 v, int d) {
    return mkf2(__shfl_down(v.x, d, 64), __shfl_down(v.y, d, 64));
}
__device__ __forceinline__ f2 shfl_f2(f2 v, int src) {
    return mkf2(__shfl(v.x, src, 64), __shfl(v.y, src, 64));
}
__device__ __forceinline__ f2 clamp01_f2(f2 a) {
    a.x = fminf(fmaxf(a.x, 0.0f), 1.0f);
    a.y = fminf(fmaxf(a.y, 0.0f), 1.0f);
    return a;
}

// native exp2/log2 (v_exp_f32 / v_log_f32, <=1 ulp). x must be > 0.
__device__ __forceinline__ float fastpow(float x, float y) {
    return __builtin_amdgcn_exp2f(y * __builtin_amdgcn_logf(x));
}

// packed rgb2lab: component .x = pred, .y = tgt.
__device__ __forceinline__ void rgb2lab_pk(f2 r, f2 g, f2 b, f2 lab[3]) {
    f2 v[3] = {r, g, b};
    f2 lin[3];
    #pragma unroll
    for (int c = 0; c < 3; ++c) {
        f2 x = v[c];
        float hx = fastpow((fmaxf(x.x, 1e-4f) + 0.055f) * (float)(1.0/1.055), 2.4f);
        float hy = fastpow((fmaxf(x.y, 1e-4f) + 0.055f) * (float)(1.0/1.055), 2.4f);
        lin[c].x = (x.x <= 0.04045f) ? x.x * (float)(1.0/12.92) : hx;
        lin[c].y = (x.y <= 0.04045f) ? x.y * (float)(1.0/12.92) : hy;
    }
    f2 X = 0.412453f*lin[0] + 0.357580f*lin[1] + 0.180423f*lin[2];
    f2 Y = 0.212671f*lin[0] + 0.715160f*lin[1] + 0.072169f*lin[2];
    f2 Z = 0.019334f*lin[0] + 0.119193f*lin[1] + 0.950227f*lin[2];
    X = X * (float)(1.0/0.950456);
    Z = Z * (float)(1.0/1.088754);
    const float eps3   = (float)((6.0/29.0)*(6.0/29.0)*(6.0/29.0));
    const float rd3e2  = (float)(1.0/(3.0*(6.0/29.0)*(6.0/29.0)));
    const float c429   = (float)(4.0/29.0);
    f2 xyz[3] = {X, Y, Z};
    f2 f[3];
    #pragma unroll
    for (int c = 0; c < 3; ++c) {
        float ax = xyz[c].x, ay = xyz[c].y;
        f[c].x = (ax <= eps3) ? (ax * rd3e2 + c429) : fastpow(fmaxf(ax, 1e-4f), (float)(1.0/3.0));
        f[c].y = (ay <= eps3) ? (ay * rd3e2 + c429) : fastpow(fmaxf(ay, 1e-4f), (float)(1.0/3.0));
    }
    f2 L  = 116.0f*f[1] - 16.0f;
    f2 A  = 500.0f*f[0] - 500.0f*f[1];
    f2 Bc = 200.0f*f[1] - 200.0f*f[2];
    lab[0] = L * 0.01f;
    lab[1] = (A * (float)(1.0/110.0) + 1.0f) * 0.5f;
    lab[2] = (Bc * (float)(1.0/110.0) + 1.0f) * 0.5f;
}

#define TST 37   // LDS row stride for 36-wide tiles

// packed separable 5x5 Gaussian SSIM over a 36x36 f2 tile ({pred,tgt} interleaved).
__device__ __forceinline__ void conv_ssim(const f2* tile, int t, float& ssum, float& csum) {
    double gd[5]; double gs = 0.0;
    #pragma unroll
    for (int i = 0; i < 5; ++i) { gd[i] = exp(-(double)((i-2)*(i-2)) / 4.5); gs += gd[i]; }
    float gw[5];
    #pragma unroll
    for (int i = 0; i < 5; ++i) gw[i] = (float)(gd[i] / gs);

    int lx = t & 31;
    int yg = t >> 5;

    f2 rA[8], rB[8];     // {m1,m2}, {m11,m22}
    float r12[8];
    #pragma unroll
    for (int k = 0; k < 8; ++k) {
        int row = yg * 4 + k;
        const f2* p = &tile[row * TST + lx];
        f2 sA = {0.f, 0.f}, sB = {0.f, 0.f};
        float s12 = 0.f;
        #pragma unroll
        for (int dx = 0; dx < 5; ++dx) {
            f2 av = p[dx];
            float wv = gw[dx];
            sA += wv * av;
            f2 sq = av * av;
            sB += wv * sq;
            s12 = fmaf(wv, av.x * av.y, s12);
        }
        rA[k] = sA; rB[k] = sB; r12[k] = s12;
    }

    const float C1 = (float)(0.01 * 0.01);
    const float C2 = (float)(0.03 * 0.03);
    ssum = 0.f; csum = 0.f;
    #pragma unroll
    for (int j = 0; j < 4; ++j) {
        f2 mA = {0.f, 0.f}, mB = {0.f, 0.f};
        float m12 = 0.f;
        #pragma unroll
        for (int k = 0; k < 5; ++k) {
            float wv = gw[k];
            mA += wv * rA[j + k];
            mB += wv * rB[j + k];
            m12 = fmaf(wv, r12[j + k], m12);
        }
        float m1 = mA.x, m2 = mA.y;
        float v1  = mB.x - m1 * m1;
        float v2  = mB.y - m2 * m2;
        float v12 = m12 - m1 * m2;
        float den2 = v1 + v2 + C2;
        ssum += ((2.0f*m1*m2 + C1) * (2.0f*v12 + C2)) / ((m1*m1 + m2*m2 + C1) * den2);
        csum += (2.0f*v12 + C2) / den2;
    }
}

__device__ __forceinline__ void halo_coords(int h, int& hr, int& hc) {
    if (h < 72)       { hr = h / 36;            hc = h % 36; }
    else if (h < 144) { int u = h - 72;  hr = 34 + u / 36; hc = u % 36; }
    else              { int u = h - 144; hr = 2 + (u >> 2); int q = u & 3; hc = (q < 2) ? q : 32 + q; }
}

// Fused: LAB + hist partial + lvl0 SSIM (halo recompute, prefetched) + full pyramid.
// One block = one 32x32 tile. grid (256, B) x 256; 4 px/thread.
__global__ void lab_ssim0_kernel(const float* __restrict__ pred,
                                 const float* __restrict__ tgt,
                                 unsigned* __restrict__ histPart,
                                 float* __restrict__ labPart,
                                 double* __restrict__ accs,
                                 float* __restrict__ ppyr,
                                 float* __restrict__ tpyr) {
    __shared__ f2 ls[36 * TST];          // packed {Lp, Lt} halo tile
    __shared__ unsigned lhist[6 * NBINS];
    __shared__ f2 s1[16 * 16];           // packed L1
    __shared__ float red12[12];

    int t  = threadIdx.x;
    int b  = blockIdx.y;
    int bx = blockIdx.x;

    for (int i = t; i < 6 * NBINS; i += 256) lhist[i] = 0;
    __syncthreads();                                            // B1

    // XCD-aware swizzle: consecutive dispatch ids -> disjoint 2-tile-row strips
    int tile = ((bx & 7) << 5) | (bx >> 3);
    int tx0 = (tile & 15) << 5;
    int ty0 = (tile >> 4) << 5;
    int r   = t >> 3;            // row within tile (0..31)
    int c4  = (t & 7) << 2;      // col within tile (0,4,..,28)
    int gy  = ty0 + r;

    const float* pimg = pred + (size_t)b * 3 * HW;
    const float* timg = tgt  + (size_t)b * 3 * HW;
    size_t ibase = (size_t)gy * IMW + tx0 + c4;

    // ---- issue ALL loads up front (interior 6x float4 + halo px t's 6 scalars) ----
    float prA[4], pgA[4], pbA[4], trA[4], tgA[4], tbA[4];
    *(float4*)&prA[0] = *(const float4*)(pimg + ibase);
    *(float4*)&pgA[0] = *(const float4*)(pimg + ibase + HW);
    *(float4*)&pbA[0] = *(const float4*)(pimg + ibase + 2*HW);
    *(float4*)&trA[0] = *(const float4*)(timg + ibase);
    *(float4*)&tgA[0] = *(const float4*)(timg + ibase + HW);
    *(float4*)&tbA[0] = *(const float4*)(timg + ibase + 2*HW);

    int hr0, hc0;
    halo_coords(t, hr0, hc0);
    int hy0 = ty0 - 2 + hr0;
    int hx0 = tx0 - 2 + hc0;
    bool hv0 = ((unsigned)hy0 < 512u) && ((unsigned)hx0 < 512u);
    size_t ho = hv0 ? ((size_t)hy0 * IMW + hx0) : 0;   // clamped addr, masked later
    float h_pr = pimg[ho], h_pg = pimg[ho + HW], h_pb = pimg[ho + 2*HW];
    float h_tr = timg[ho], h_tg = timg[ho + HW], h_tb = timg[ho + 2*HW];

    // ---- interior compute (halo loads in flight) ----
    float l1 = 0.0f;
    f2 pL[4];
    #pragma unroll
    for (int k = 0; k < 4; ++k) {
        f2 lab[3];
        rgb2lab_pk(mkf2(prA[k], trA[k]), mkf2(pgA[k], tgA[k]), mkf2(pbA[k], tbA[k]), lab);
        #pragma unroll
        for (int c = 0; c < 3; ++c) {
            f2 lc = clamp01_f2(lab[c]);
            l1 += fabsf(lc.x - lc.y);
            int ip = min(max((int)floorf(lc.x * (float)NBINS), 0), NBINS - 1);
            int it = min(max((int)floorf(lc.y * (float)NBINS), 0), NBINS - 1);
            atomicAdd(&lhist[c * NBINS + ip], 1u);
            atomicAdd(&lhist[(3 + c) * NBINS + it], 1u);
            if (c == 0) pL[k] = lc;
        }
        ls[(r + 2) * TST + (c4 + 2 + k)] = pL[k];
    }

    // ---- halo px t (prefetched) ----
    {
        f2 lab[3];
        rgb2lab_pk(mkf2(h_pr, h_tr), mkf2(h_pg, h_tg), mkf2(h_pb, h_tb), lab);
        f2 Lv = hv0 ? clamp01_f2(lab[0]) : mkf2(0.f, 0.f);
        ls[hr0 * TST + hc0] = Lv;
    }
    // ---- remaining 16 halo px (t < 16) ----
    if (t < 16) {
        int hr, hc;
        halo_coords(256 + t, hr, hc);
        int hy = ty0 - 2 + hr;
        int hx = tx0 - 2 + hc;
        f2 Lv = {0.f, 0.f};
        if ((unsigned)hy < 512u && (unsigned)hx < 512u) {
            size_t o = (size_t)hy * IMW + hx;
            f2 lab[3];
            rgb2lab_pk(mkf2(pimg[o], timg[o]),
                       mkf2(pimg[o + HW], timg[o + HW]),
                       mkf2(pimg[o + 2*HW], timg[o + 2*HW]), lab);
            Lv = clamp01_f2(lab[0]);
        }
        ls[hr * TST + hc] = Lv;
    }
    __syncthreads();                                            // B2

    // non-atomic per-block histogram partial, u16-packed two bins per u32
    unsigned* hp = histPart + ((size_t)b * 256 + bx) * 768;
    for (int i = t; i < 768; i += 256)
        hp[i] = (lhist[2*i] & 0xFFFFu) | (lhist[2*i + 1] << 16);

    // pyramid L1 from registers (shuffles), packed
    float* pyrP = ppyr + (size_t)b * PYR_PER_IMG;
    float* pyrT = tpyr + (size_t)b * PYR_PER_IMG;
    f2 ph0 = pL[0] + pL[1], ph1 = pL[2] + pL[3];
    f2 ph0b = shfl_down_f2(ph0, 8);
    f2 ph1b = shfl_down_f2(ph1, 8);
    if ((t & 8) == 0) {                 // even row r
        int y1 = r >> 1;
        int x1 = (t & 7) << 1;
        f2 v0 = 0.25f * (ph0 + ph0b);
        f2 v1 = 0.25f * (ph1 + ph1b);
        s1[y1 * 16 + x1]     = v0;
        s1[y1 * 16 + x1 + 1] = v1;
        int g1 = ((ty0 >> 1) + y1) * 256 + (tx0 >> 1) + x1;
        *(float2*)&pyrP[PYR_OFF_L1 + g1] = make_float2(v0.x, v1.x);
        *(float2*)&pyrT[PYR_OFF_L1 + g1] = make_float2(v0.y, v1.y);
    }
    __syncthreads();                                            // B3

    // lvl0 SSIM from packed LDS tile
    float ssum, csum;
    conv_ssim(ls, t, ssum, csum);

    // pyramid L2-L4: wave 0 only (shuffle cascade, no barriers)
    if (t < 64) {
        int y2 = t >> 3, x2 = t & 7;
        const f2* s = &s1[(2*y2) * 16 + 2*x2];
        f2 v2 = 0.25f * (s[0] + s[1] + s[16] + s[17]);
        pyrP[PYR_OFF_L2 + ((ty0 >> 2) + y2) * 128 + (tx0 >> 2) + x2] = v2.x;
        pyrT[PYR_OFF_L2 + ((ty0 >> 2) + y2) * 128 + (tx0 >> 2) + x2] = v2.y;

        int y3 = (t >> 2) & 3, x3 = t & 3;
        f2 v3 = 0.25f * (shfl_f2(v2, (2*y3)*8 + 2*x3)     + shfl_f2(v2, (2*y3)*8 + 2*x3 + 1) +
                         shfl_f2(v2, (2*y3+1)*8 + 2*x3)   + shfl_f2(v2, (2*y3+1)*8 + 2*x3 + 1));
        if (t < 16) {
            pyrP[PYR_OFF_L3 + ((ty0 >> 3) + y3) * 64 + (tx0 >> 3) + x3] = v3.x;
            pyrT[PYR_OFF_L3 + ((ty0 >> 3) + y3) * 64 + (tx0 >> 3) + x3] = v3.y;
        }
        int y4 = (t >> 1) & 1, x4 = t & 1;
        f2 v4 = 0.25f * (shfl_f2(v3, (2*y4)*4 + 2*x4)     + shfl_f2(v3, (2*y4)*4 + 2*x4 + 1) +
                         shfl_f2(v3, (2*y4+1)*4 + 2*x4)   + shfl_f2(v3, (2*y4+1)*4 + 2*x4 + 1));
        if (t < 4) {
            pyrP[PYR_OFF_L4 + ((ty0 >> 4) + y4) * 32 + (tx0 >> 4) + x4] = v4.x;
            pyrT[PYR_OFF_L4 + ((ty0 >> 4) + y4) * 32 + (tx0 >> 4) + x4] = v4.y;
        }
    }

    // single combined reduction: l1, ssum, csum
    int lane = t & 63;
    int wid  = t >> 6;
    #pragma unroll
    for (int o = 32; o >= 1; o >>= 1) {
        l1   += __shfl_down(l1, o, 64);
        ssum += __shfl_down(ssum, o, 64);
        csum += __shfl_down(csum, o, 64);
    }
    if (lane == 0) {
        red12[wid * 3 + 0] = l1;
        red12[wid * 3 + 1] = ssum;
        red12[wid * 3 + 2] = csum;
    }
    __syncthreads();                                            // B4
    if (t < 4) {
        float a0 = red12[t * 3 + 0];
        float a1 = red12[t * 3 + 1];
        float a2 = red12[t * 3 + 2];
        #pragma unroll
        for (int o = 2; o >= 1; o >>= 1) {
            a0 += __shfl_down(a0, o, 64);
            a1 += __shfl_down(a1, o, 64);
            a2 += __shfl_down(a2, o, 64);
        }
        if (t == 0) {
            labPart[b * 256 + bx] = a0;
            atomicAdd(&accs[b * 5 + 0], (double)a1);        // sAcc lvl0
            atomicAdd(&accs[40 + b * 5 + 0], (double)a2);   // cAcc lvl0
        }
    }
}

// Merged tail: 729 blocks.
//   bx < 48           : hist partial reduce — 6 blocks/image, 64 words each;
//                       256 threads = 64 words x 4 tile-chunks of 64 tiles.
//                       Coalesced lanes AND short chains (64 iters, unroll 8).
//                       Placed first so long-latency blocks launch early.
//   bx == 48          : labPart reduce
//   49 <= bx < 729    : SSIM levels 1-4 (85 per image)
// Last finishing block computes the final outputs.
__global__ void tail_kernel(const float* __restrict__ ppyr,
                            const float* __restrict__ tpyr,
                            const unsigned* __restrict__ histPart,
                            const float* __restrict__ labPart,
                            double* __restrict__ accs,
                            float* __restrict__ out) {
    __shared__ f2 tls[36 * TST];
    __shared__ float red12[12];
    __shared__ int dLo[256];
    __shared__ int dHi[256];
    int t = threadIdx.x;
    int bx = blockIdx.x;
    double* histL1acc = accs + 80;
    double* labSumD   = accs + 88;
    unsigned* counter = (unsigned*)(accs + 89);

    if (bx < 48) {
        int b  = bx / 6;                       // image
        int w  = (bx % 6) * 64 + (t & 63);     // packed word within image
        int ck = t >> 6;                       // tile chunk 0..3 (64 tiles each)
        const unsigned* p = histPart + (size_t)b * 256 * 768 + (size_t)(ck * 64) * 768;
        unsigned sPlo = 0, sPhi = 0, sTlo = 0, sThi = 0;
        #pragma unroll 8
        for (int i = 0; i < 64; ++i) {
            unsigned wP = p[(size_t)i * 768 + w];          // lanes contiguous
            unsigned wT = p[(size_t)i * 768 + 384 + w];
            sPlo += wP & 0xFFFFu;  sPhi += wP >> 16;
            sTlo += wT & 0xFFFFu;  sThi += wT >> 16;
        }
        dLo[t] = (int)sPlo - (int)sTlo;        // exact signed partial diffs
        dHi[t] = (int)sPhi - (int)sThi;
        __syncthreads();
        if (t < 64) {                          // wave 0: combine 4 chunks per word
            int lo = dLo[t] + dLo[t + 64] + dLo[t + 128] + dLo[t + 192];
            int hi = dHi[t] + dHi[t + 64] + dHi[t + 128] + dHi[t + 192];
            float val = fabsf((float)lo) + fabsf((float)hi);   // exact: |.| < 2^24
            #pragma unroll
            for (int o = 32; o >= 1; o >>= 1) val += __shfl_down(val, o, 64);
            if (t == 0) atomicAdd(&histL1acc[b], (double)val);
        }
        __syncthreads();
    } else if (bx == 48) {
        float s = 0.0f;
        #pragma unroll
        for (int k = 0; k < 8; ++k) s += labPart[t + k * 256];
        int lane = t & 63;
        int wid  = t >> 6;
        #pragma unroll
        for (int o = 32; o >= 1; o >>= 1) s += __shfl_down(s, o, 64);
        if (lane == 0) red12[wid * 3] = s;
        __syncthreads();
        if (t == 0) labSumD[0] = (double)(red12[0] + red12[3] + red12[6] + red12[9]);
    } else {
        int cb = bx - 49;
        int b = cb / 85;
        int sub = cb - b * 85;
        int lvl, pblk;
        if (sub < 64)      { lvl = 1; pblk = sub; }
        else if (sub < 80) { lvl = 2; pblk = sub - 64; }
        else if (sub < 84) { lvl = 3; pblk = sub - 80; }
        else               { lvl = 4; pblk = 0; }

        const int offs[5] = {0, PYR_OFF_L1, PYR_OFF_L2, PYR_OFF_L3, PYR_OFF_L4};
        int w = 512 >> lvl;
        const float* i1 = ppyr + (size_t)b * PYR_PER_IMG + offs[lvl];
        const float* i2 = tpyr + (size_t)b * PYR_PER_IMG + offs[lvl];

        int tprShift = 4 - lvl;
        int ty0 = (pblk >> tprShift) << 5;
        int tx0 = (pblk & ((1 << tprShift) - 1)) << 5;

        for (int i = t; i < 36 * 36; i += 256) {
            int r = i / 36, c = i % 36;
            int gy = ty0 - 2 + r;
            int gx = tx0 - 2 + c;
            bool ok = ((unsigned)gy < (unsigned)w) && ((unsigned)gx < (unsigned)w);
            int gi = gy * w + gx;
            tls[r * TST + c] = ok ? mkf2(i1[gi], i2[gi]) : mkf2(0.f, 0.f);
        }
        __syncthreads();

        float ssum, csum;
        conv_ssim(tls, t, ssum, csum);

        int lane = t & 63;
        int wid  = t >> 6;
        #pragma unroll
        for (int o = 32; o >= 1; o >>= 1) {
            ssum += __shfl_down(ssum, o, 64);
            csum += __shfl_down(csum, o, 64);
        }
        if (lane == 0) {
            red12[wid * 3 + 0] = ssum;
            red12[wid * 3 + 1] = csum;
        }
        __syncthreads();
        if (t < 4) {
            float a1 = red12[t * 3 + 0];
            float a2 = red12[t * 3 + 1];
            #pragma unroll
            for (int o = 2; o >= 1; o >>= 1) {
                a1 += __shfl_down(a1, o, 64);
                a2 += __shfl_down(a2, o, 64);
            }
            if (t == 0) {
                atomicAdd(&accs[b * 5 + lvl], (double)a1);
                atomicAdd(&accs[40 + b * 5 + lvl], (double)a2);
            }
        }
    }

    __syncthreads();
    if (t == 0) {
        __threadfence();
        unsigned old = atomicAdd(counter, 1u);
        if (old == 728u) {            // last of 729 blocks
            __threadfence();
            volatile double* vacc = accs;
            float hist_loss = 0.0f;
            for (int b = 0; b < B; ++b) {
                float l1 = (float)(vacc[80 + b] / (double)(3 * NBINS));
                float wgt = exp2f((float)(b - B));   // 2^(b - n), n = B = 8
                hist_loss += wgt * (l1 + 1.0f);
            }
            float scaler = (float)HW / 20.0f;
            hist_loss = hist_loss / (float)B / scaler;
            float lab_l1 = (float)(vacc[88] / (double)((size_t)B * 3 * HW));
            out[0] = lab_l1 + hist_loss;

            const float msw[5] = {0.0448f, 0.2856f, 0.3001f, 0.2363f, 0.1333f};
            const int npix[5] = {HW, HW/4, HW/16, HW/64, HW/256};
            float loss = 0.0f;
            for (int b = 0; b < B; ++b) {
                float ms = 1.0f;
                for (int l = 0; l < 4; ++l) {
                    float cs = (float)(vacc[40 + b * 5 + l] / (double)npix[l]);
                    float csn = (cs + 1.0f) / 2.0f;
                    ms *= powf(csn, msw[l]);
                }
                float sm = (float)(vacc[b * 5 + 4] / (double)npix[4]);
                float smn = (sm + 1.0f) / 2.0f;
                ms *= powf(smn, msw[4]);
                loss += 1.0f - ms;
            }
            out[1] = loss / (float)B;
        }
    }
}

extern "C" void kernel_launch(void* const* d_in, const int* in_sizes, int n_in,
                              void* d_out, int out_size, void* d_ws, size_t ws_size,
                              hipStream_t stream) {
    const float* pred = (const float*)d_in[1];
    const float* tgt  = (const float*)d_in[2];
    float* ws_f = (float*)d_ws;

    float* ppyr  = ws_f + OFF_PPYR;
    float* tpyr  = ws_f + OFF_TPYR;
    unsigned* histPart = (unsigned*)(ws_f + OFF_HISTPART);
    float* labPart = ws_f + OFF_LABPART;
    double* accs = (double*)(ws_f + OFF_ACC);
    float* out = (float*)d_out;

    // zero accumulators + completion counter (90 doubles)
    hipMemsetAsync(accs, 0, 90 * sizeof(double), stream);

    lab_ssim0_kernel<<<dim3(256, B), 256, 0, stream>>>(pred, tgt, histPart, labPart,
                                                       accs, ppyr, tpyr);

    tail_kernel<<<729, 256, 0, stream>>>(ppyr, tpyr, histPart, labPart, accs, out);
}

// Round 11
// 139.592 us; speedup vs baseline: 1.2471x; 1.1771x over previous
//
#include <hip/hip_runtime.h>
#include <math.h>

#define B 8
#define IMH 512
#define IMW 512
#define HW (IMH*IMW)
#define NBINS 256

// pyramid per-image: levels 1..4 (256^2, 128^2, 64^2, 32^2)
#define PYR_PER_IMG (65536 + 16384 + 4096 + 1024)   // 87040
#define PYR_OFF_L1 0
#define PYR_OFF_L2 65536
#define PYR_OFF_L3 81920
#define PYR_OFF_L4 86016

// workspace float-index offsets
#define OFF_PPYR 0
#define OFF_TPYR (B*PYR_PER_IMG)
#define OFF_HISTPART (2*B*PYR_PER_IMG)              // u32: B*256*768 (u16-packed bins)
#define OFF_LABPART  (OFF_HISTPART + B*256*768)     // float: 2048
#define OFF_ACC      (OFF_LABPART + 2048)           // byte offset % 8 == 0
// doubles: sAcc[40], cAcc[40], histL1acc[8], labSumD[1], counter[1 slot] = 90

typedef float f2 __attribute__((ext_vector_type(2)));

__device__ __forceinline__ f2 mkf2(float a, float b) { f2 r; r.x = a; r.y = b; return r; }
__device__ __forceinline__ f2 shfl_down_f2(f2 v, int d) {
    return mkf2(__shfl_down(v.x, d, 64), __shfl_down(v.y, d, 64));
}
__device__ __forceinline__ f2 shfl_f2(f2 v, int src) {
    return mkf2(__shfl(v.x, src, 64), __shfl(v.y, src, 64));
}
__device__ __forceinline__ f2 clamp01_f2(f2 a) {
    a.x = fminf(fmaxf(a.x, 0.0f), 1.0f);
    a.y = fminf(fmaxf(a.y, 0.0f), 1.0f);
    return a;
}

// native exp2/log2 (v_exp_f32 / v_log_f32, <=1 ulp). x must be > 0.
__device__ __forceinline__ float fastpow(float x, float y) {
    return __builtin_amdgcn_exp2f(y * __builtin_amdgcn_logf(x));
}

// packed rgb2lab: component .x = pred, .y = tgt.
__device__ __forceinline__ void rgb2lab_pk(f2 r, f2 g, f2 b, f2 lab[3]) {
    f2 v[3] = {r, g, b};
    f2 lin[3];
    #pragma unroll
    for (int c = 0; c < 3; ++c) {
        f2 x = v[c];
        float hx = fastpow((fmaxf(x.x, 1e-4f) + 0.055f) * (float)(1.0/1.055), 2.4f);
        float hy = fastpow((fmaxf(x.y, 1e-4f) + 0.055f) * (float)(1.0/1.055), 2.4f);
        lin[c].x = (x.x <= 0.04045f) ? x.x * (float)(1.0/12.92) : hx;
        lin[c].y = (x.y <= 0.04045f) ? x.y * (float)(1.0/12.92) : hy;
    }
    f2 X = 0.412453f*lin[0] + 0.357580f*lin[1] + 0.180423f*lin[2];
    f2 Y = 0.212671f*lin[0] + 0.715160f*lin[1] + 0.072169f*lin[2];
    f2 Z = 0.019334f*lin[0] + 0.119193f*lin[1] + 0.950227f*lin[2];
    X = X * (float)(1.0/0.950456);
    Z = Z * (float)(1.0/1.088754);
    const float eps3   = (float)((6.0/29.0)*(6.0/29.0)*(6.0/29.0));
    const float rd3e2  = (float)(1.0/(3.0*(6.0/29.0)*(6.0/29.0)));
    const float c429   = (float)(4.0/29.0);
    f2 xyz[3] = {X, Y, Z};
    f2 f[3];
    #pragma unroll
    for (int c = 0; c < 3; ++c) {
        float ax = xyz[c].x, ay = xyz[c].y;
        f[c].x = (ax <= eps3) ? (ax * rd3e2 + c429) : fastpow(fmaxf(ax, 1e-4f), (float)(1.0/3.0));
        f[c].y = (ay <= eps3) ? (ay * rd3e2 + c429) : fastpow(fmaxf(ay, 1e-4f), (float)(1.0/3.0));
    }
    f2 L  = 116.0f*f[1] - 16.0f;
    f2 A  = 500.0f*f[0] - 500.0f*f[1];
    f2 Bc = 200.0f*f[1] - 200.0f*f[2];
    lab[0] = L * 0.01f;
    lab[1] = (A * (float)(1.0/110.0) + 1.0f) * 0.5f;
    lab[2] = (Bc * (float)(1.0/110.0) + 1.0f) * 0.5f;
}

#define TST 37   // LDS row stride for 36-wide tiles

// packed separable 5x5 Gaussian SSIM over a 36x36 f2 tile ({pred,tgt} interleaved).
// v_rcp_f32 instead of precise div (rel err ~1e-7, threshold 7e-3).
__device__ __forceinline__ void conv_ssim(const f2* tile, int t, float& ssum, float& csum) {
    double gd[5]; double gs = 0.0;
    #pragma unroll
    for (int i = 0; i < 5; ++i) { gd[i] = exp(-(double)((i-2)*(i-2)) / 4.5); gs += gd[i]; }
    float gw[5];
    #pragma unroll
    for (int i = 0; i < 5; ++i) gw[i] = (float)(gd[i] / gs);

    int lx = t & 31;
    int yg = t >> 5;

    f2 rA[8], rB[8];     // {m1,m2}, {m11,m22}
    float r12[8];
    #pragma unroll
    for (int k = 0; k < 8; ++k) {
        int row = yg * 4 + k;
        const f2* p = &tile[row * TST + lx];
        f2 sA = {0.f, 0.f}, sB = {0.f, 0.f};
        float s12 = 0.f;
        #pragma unroll
        for (int dx = 0; dx < 5; ++dx) {
            f2 av = p[dx];
            float wv = gw[dx];
            sA += wv * av;
            f2 sq = av * av;
            sB += wv * sq;
            s12 = fmaf(wv, av.x * av.y, s12);
        }
        rA[k] = sA; rB[k] = sB; r12[k] = s12;
    }

    const float C1 = (float)(0.01 * 0.01);
    const float C2 = (float)(0.03 * 0.03);
    ssum = 0.f; csum = 0.f;
    #pragma unroll
    for (int j = 0; j < 4; ++j) {
        f2 mA = {0.f, 0.f}, mB = {0.f, 0.f};
        float m12 = 0.f;
        #pragma unroll
        for (int k = 0; k < 5; ++k) {
            float wv = gw[k];
            mA += wv * rA[j + k];
            mB += wv * rB[j + k];
            m12 = fmaf(wv, r12[j + k], m12);
        }
        float m1 = mA.x, m2 = mA.y;
        float v1  = mB.x - m1 * m1;
        float v2  = mB.y - m2 * m2;
        float v12 = m12 - m1 * m2;
        float n12 = 2.0f * v12 + C2;
        float rd2 = __builtin_amdgcn_rcpf(v1 + v2 + C2);
        float rd1 = __builtin_amdgcn_rcpf(m1*m1 + m2*m2 + C1);
        csum = fmaf(n12, rd2, csum);
        ssum += (2.0f*m1*m2 + C1) * n12 * rd1 * rd2;
    }
}

__device__ __forceinline__ void halo_coords(int h, int& hr, int& hc) {
    if (h < 72)       { hr = h / 36;            hc = h % 36; }
    else if (h < 144) { int u = h - 72;  hr = 34 + u / 36; hc = u % 36; }
    else              { int u = h - 144; hr = 2 + (u >> 2); int q = u & 3; hc = (q < 2) ? q : 32 + q; }
}

// Fused: LAB + hist partial + lvl0 SSIM (halo recompute, prefetched) + full pyramid.
// One block = one 32x32 tile. grid (256, B) x 256; 4 px/thread.
__global__ void lab_ssim0_kernel(const float* __restrict__ pred,
                                 const float* __restrict__ tgt,
                                 unsigned* __restrict__ histPart,
                                 float* __restrict__ labPart,
                                 double* __restrict__ accs,
                                 float* __restrict__ ppyr,
                                 float* __restrict__ tpyr) {
    __shared__ f2 ls[36 * TST];          // packed {Lp, Lt} halo tile
    __shared__ unsigned lhist[6 * NBINS];
    __shared__ f2 s1[16 * 16];           // packed L1
    __shared__ float red12[12];

    int t  = threadIdx.x;
    int b  = blockIdx.y;
    int bx = blockIdx.x;

    for (int i = t; i < 6 * NBINS; i += 256) lhist[i] = 0;
    __syncthreads();                                            // B1

    // XCD-aware swizzle: consecutive dispatch ids -> disjoint 2-tile-row strips
    int tile = ((bx & 7) << 5) | (bx >> 3);
    int tx0 = (tile & 15) << 5;
    int ty0 = (tile >> 4) << 5;
    int r   = t >> 3;            // row within tile (0..31)
    int c4  = (t & 7) << 2;      // col within tile (0,4,..,28)
    int gy  = ty0 + r;

    const float* pimg = pred + (size_t)b * 3 * HW;
    const float* timg = tgt  + (size_t)b * 3 * HW;
    size_t ibase = (size_t)gy * IMW + tx0 + c4;

    // ---- issue ALL loads up front (interior 6x float4 + halo px t's 6 scalars) ----
    float prA[4], pgA[4], pbA[4], trA[4], tgA[4], tbA[4];
    *(float4*)&prA[0] = *(const float4*)(pimg + ibase);
    *(float4*)&pgA[0] = *(const float4*)(pimg + ibase + HW);
    *(float4*)&pbA[0] = *(const float4*)(pimg + ibase + 2*HW);
    *(float4*)&trA[0] = *(const float4*)(timg + ibase);
    *(float4*)&tgA[0] = *(const float4*)(timg + ibase + HW);
    *(float4*)&tbA[0] = *(const float4*)(timg + ibase + 2*HW);

    int hr0, hc0;
    halo_coords(t, hr0, hc0);
    int hy0 = ty0 - 2 + hr0;
    int hx0 = tx0 - 2 + hc0;
    bool hv0 = ((unsigned)hy0 < 512u) && ((unsigned)hx0 < 512u);
    size_t ho = hv0 ? ((size_t)hy0 * IMW + hx0) : 0;   // clamped addr, masked later
    float h_pr = pimg[ho], h_pg = pimg[ho + HW], h_pb = pimg[ho + 2*HW];
    float h_tr = timg[ho], h_tg = timg[ho + HW], h_tb = timg[ho + 2*HW];

    // ---- interior compute (halo loads in flight) ----
    float l1 = 0.0f;
    f2 pL[4];
    #pragma unroll
    for (int k = 0; k < 4; ++k) {
        f2 lab[3];
        rgb2lab_pk(mkf2(prA[k], trA[k]), mkf2(pgA[k], tgA[k]), mkf2(pbA[k], tbA[k]), lab);
        #pragma unroll
        for (int c = 0; c < 3; ++c) {
            f2 lc = clamp01_f2(lab[c]);
            l1 += fabsf(lc.x - lc.y);
            int ip = min(max((int)floorf(lc.x * (float)NBINS), 0), NBINS - 1);
            int it = min(max((int)floorf(lc.y * (float)NBINS), 0), NBINS - 1);
            atomicAdd(&lhist[c * NBINS + ip], 1u);
            atomicAdd(&lhist[(3 + c) * NBINS + it], 1u);
            if (c == 0) pL[k] = lc;
        }
        ls[(r + 2) * TST + (c4 + 2 + k)] = pL[k];
    }

    // ---- halo px t (prefetched) ----
    {
        f2 lab[3];
        rgb2lab_pk(mkf2(h_pr, h_tr), mkf2(h_pg, h_tg), mkf2(h_pb, h_tb), lab);
        f2 Lv = hv0 ? clamp01_f2(lab[0]) : mkf2(0.f, 0.f);
        ls[hr0 * TST + hc0] = Lv;
    }
    // ---- remaining 16 halo px (t < 16) ----
    if (t < 16) {
        int hr, hc;
        halo_coords(256 + t, hr, hc);
        int hy = ty0 - 2 + hr;
        int hx = tx0 - 2 + hc;
        f2 Lv = {0.f, 0.f};
        if ((unsigned)hy < 512u && (unsigned)hx < 512u) {
            size_t o = (size_t)hy * IMW + hx;
            f2 lab[3];
            rgb2lab_pk(mkf2(pimg[o], timg[o]),
                       mkf2(pimg[o + HW], timg[o + HW]),
                       mkf2(pimg[o + 2*HW], timg[o + 2*HW]), lab);
            Lv = clamp01_f2(lab[0]);
        }
        ls[hr * TST + hc] = Lv;
    }
    __syncthreads();                                            // B2

    // non-atomic per-block histogram partial, u16-packed two bins per u32
    unsigned* hp = histPart + ((size_t)b * 256 + bx) * 768;
    for (int i = t; i < 768; i += 256)
        hp[i] = (lhist[2*i] & 0xFFFFu) | (lhist[2*i + 1] << 16);

    // pyramid L1 from registers (shuffles), packed
    float* pyrP = ppyr + (size_t)b * PYR_PER_IMG;
    float* pyrT = tpyr + (size_t)b * PYR_PER_IMG;
    f2 ph0 = pL[0] + pL[1], ph1 = pL[2] + pL[3];
    f2 ph0b = shfl_down_f2(ph0, 8);
    f2 ph1b = shfl_down_f2(ph1, 8);
    if ((t & 8) == 0) {                 // even row r
        int y1 = r >> 1;
        int x1 = (t & 7) << 1;
        f2 v0 = 0.25f * (ph0 + ph0b);
        f2 v1 = 0.25f * (ph1 + ph1b);
        s1[y1 * 16 + x1]     = v0;
        s1[y1 * 16 + x1 + 1] = v1;
        int g1 = ((ty0 >> 1) + y1) * 256 + (tx0 >> 1) + x1;
        *(float2*)&pyrP[PYR_OFF_L1 + g1] = make_float2(v0.x, v1.x);
        *(float2*)&pyrT[PYR_OFF_L1 + g1] = make_float2(v0.y, v1.y);
    }
    __syncthreads();                                            // B3

    // lvl0 SSIM from packed LDS tile
    float ssum, csum;
    conv_ssim(ls, t, ssum, csum);

    // pyramid L2-L4: wave 0 only (shuffle cascade, no barriers)
    if (t < 64) {
        int y2 = t >> 3, x2 = t & 7;
        const f2* s = &s1[(2*y2) * 16 + 2*x2];
        f2 v2 = 0.25f * (s[0] + s[1] + s[16] + s[17]);
        pyrP[PYR_OFF_L2 + ((ty0 >> 2) + y2) * 128 + (tx0 >> 2) + x2] = v2.x;
        pyrT[PYR_OFF_L2 + ((ty0 >> 2) + y2) * 128 + (tx0 >> 2) + x2] = v2.y;

        int y3 = (t >> 2) & 3, x3 = t & 3;
        f2 v3 = 0.25f * (shfl_f2(v2, (2*y3)*8 + 2*x3)     + shfl_f2(v2, (2*y3)*8 + 2*x3 + 1) +
                         shfl_f2(v2, (2*y3+1)*8 + 2*x3)   + shfl_f2(v2, (2*y3+1)*8 + 2*x3 + 1));
        if (t < 16) {
            pyrP[PYR_OFF_L3 + ((ty0 >> 3) + y3) * 64 + (tx0 >> 3) + x3] = v3.x;
            pyrT[PYR_OFF_L3 + ((ty0 >> 3) + y3) * 64 + (tx0 >> 3) + x3] = v3.y;
        }
        int y4 = (t >> 1) & 1, x4 = t & 1;
        f2 v4 = 0.25f * (shfl_f2(v3, (2*y4)*4 + 2*x4)     + shfl_f2(v3, (2*y4)*4 + 2*x4 + 1) +
                         shfl_f2(v3, (2*y4+1)*4 + 2*x4)   + shfl_f2(v3, (2*y4+1)*4 + 2*x4 + 1));
        if (t < 4) {
            pyrP[PYR_OFF_L4 + ((ty0 >> 4) + y4) * 32 + (tx0 >> 4) + x4] = v4.x;
            pyrT[PYR_OFF_L4 + ((ty0 >> 4) + y4) * 32 + (tx0 >> 4) + x4] = v4.y;
        }
    }

    // single combined reduction: l1, ssum, csum
    int lane = t & 63;
    int wid  = t >> 6;
    #pragma unroll
    for (int o = 32; o >= 1; o >>= 1) {
        l1   += __shfl_down(l1, o, 64);
        ssum += __shfl_down(ssum, o, 64);
        csum += __shfl_down(csum, o, 64);
    }
    if (lane == 0) {
        red12[wid * 3 + 0] = l1;
        red12[wid * 3 + 1] = ssum;
        red12[wid * 3 + 2] = csum;
    }
    __syncthreads();                                            // B4
    if (t < 4) {
        float a0 = red12[t * 3 + 0];
        float a1 = red12[t * 3 + 1];
        float a2 = red12[t * 3 + 2];
        #pragma unroll
        for (int o = 2; o >= 1; o >>= 1) {
            a0 += __shfl_down(a0, o, 64);
            a1 += __shfl_down(a1, o, 64);
            a2 += __shfl_down(a2, o, 64);
        }
        if (t == 0) {
            labPart[b * 256 + bx] = a0;
            atomicAdd(&accs[b * 5 + 0], (double)a1);        // sAcc lvl0
            atomicAdd(&accs[40 + b * 5 + 0], (double)a2);   // cAcc lvl0
        }
    }
}

// Merged tail: 729 blocks.
//   bx < 48           : hist partial reduce — 6 blocks/image, 64 words each;
//                       256 threads = 64 words x 4 tile-chunks of 64 tiles.
//   bx == 48          : labPart reduce
//   49 <= bx < 729    : SSIM levels 1-4 (85 per image)
// Last block's wave 0 computes the final outputs IN PARALLEL (fastpow, no OCML powf).
__global__ void tail_kernel(const float* __restrict__ ppyr,
                            const float* __restrict__ tpyr,
                            const unsigned* __restrict__ histPart,
                            const float* __restrict__ labPart,
                            double* __restrict__ accs,
                            float* __restrict__ out) {
    __shared__ f2 tls[36 * TST];
    __shared__ float red12[12];
    __shared__ int dLo[256];
    __shared__ int dHi[256];
    int t = threadIdx.x;
    int bx = blockIdx.x;
    double* histL1acc = accs + 80;
    double* labSumD   = accs + 88;
    unsigned* counter = (unsigned*)(accs + 89);

    if (bx < 48) {
        int b  = bx / 6;                       // image
        int w  = (bx % 6) * 64 + (t & 63);     // packed word within image
        int ck = t >> 6;                       // tile chunk 0..3 (64 tiles each)
        const unsigned* p = histPart + (size_t)b * 256 * 768 + (size_t)(ck * 64) * 768;
        unsigned sPlo = 0, sPhi = 0, sTlo = 0, sThi = 0;
        #pragma unroll 8
        for (int i = 0; i < 64; ++i) {
            unsigned wP = p[(size_t)i * 768 + w];          // lanes contiguous
            unsigned wT = p[(size_t)i * 768 + 384 + w];
            sPlo += wP & 0xFFFFu;  sPhi += wP >> 16;
            sTlo += wT & 0xFFFFu;  sThi += wT >> 16;
        }
        dLo[t] = (int)sPlo - (int)sTlo;        // exact signed partial diffs
        dHi[t] = (int)sPhi - (int)sThi;
        __syncthreads();
        if (t < 64) {                          // wave 0: combine 4 chunks per word
            int lo = dLo[t] + dLo[t + 64] + dLo[t + 128] + dLo[t + 192];
            int hi = dHi[t] + dHi[t + 64] + dHi[t + 128] + dHi[t + 192];
            float val = fabsf((float)lo) + fabsf((float)hi);   // exact: |.| < 2^24
            #pragma unroll
            for (int o = 32; o >= 1; o >>= 1) val += __shfl_down(val, o, 64);
            if (t == 0) atomicAdd(&histL1acc[b], (double)val);
        }
        __syncthreads();
    } else if (bx == 48) {
        float s = 0.0f;
        #pragma unroll
        for (int k = 0; k < 8; ++k) s += labPart[t + k * 256];
        int lane = t & 63;
        int wid  = t >> 6;
        #pragma unroll
        for (int o = 32; o >= 1; o >>= 1) s += __shfl_down(s, o, 64);
        if (lane == 0) red12[wid * 3] = s;
        __syncthreads();
        if (t == 0) labSumD[0] = (double)(red12[0] + red12[3] + red12[6] + red12[9]);
    } else {
        int cb = bx - 49;
        int b = cb / 85;
        int sub = cb - b * 85;
        int lvl, pblk;
        if (sub < 64)      { lvl = 1; pblk = sub; }
        else if (sub < 80) { lvl = 2; pblk = sub - 64; }
        else if (sub < 84) { lvl = 3; pblk = sub - 80; }
        else               { lvl = 4; pblk = 0; }

        const int offs[5] = {0, PYR_OFF_L1, PYR_OFF_L2, PYR_OFF_L3, PYR_OFF_L4};
        int w = 512 >> lvl;
        const float* i1 = ppyr + (size_t)b * PYR_PER_IMG + offs[lvl];
        const float* i2 = tpyr + (size_t)b * PYR_PER_IMG + offs[lvl];

        int tprShift = 4 - lvl;
        int ty0 = (pblk >> tprShift) << 5;
        int tx0 = (pblk & ((1 << tprShift) - 1)) << 5;

        for (int i = t; i < 36 * 36; i += 256) {
            int r = i / 36, c = i % 36;
            int gy = ty0 - 2 + r;
            int gx = tx0 - 2 + c;
            bool ok = ((unsigned)gy < (unsigned)w) && ((unsigned)gx < (unsigned)w);
            int gi = gy * w + gx;
            tls[r * TST + c] = ok ? mkf2(i1[gi], i2[gi]) : mkf2(0.f, 0.f);
        }
        __syncthreads();

        float ssum, csum;
        conv_ssim(tls, t, ssum, csum);

        int lane = t & 63;
        int wid  = t >> 6;
        #pragma unroll
        for (int o = 32; o >= 1; o >>= 1) {
            ssum += __shfl_down(ssum, o, 64);
            csum += __shfl_down(csum, o, 64);
        }
        if (lane == 0) {
            red12[wid * 3 + 0] = ssum;
            red12[wid * 3 + 1] = csum;
        }
        __syncthreads();
        if (t < 4) {
            float a1 = red12[t * 3 + 0];
            float a2 = red12[t * 3 + 1];
            #pragma unroll
            for (int o = 2; o >= 1; o >>= 1) {
                a1 += __shfl_down(a1, o, 64);
                a2 += __shfl_down(a2, o, 64);
            }
            if (t == 0) {
                atomicAdd(&accs[b * 5 + lvl], (double)a1);
                atomicAdd(&accs[40 + b * 5 + lvl], (double)a2);
            }
        }
    }

    __syncthreads();
    if (t < 64) {
        unsigned old = 0;
        if (t == 0) { __threadfence(); old = atomicAdd(counter, 1u); }
        old = __shfl(old, 0, 64);
        if (old == 728u) {            // last of 729 blocks: parallel finish on wave 0
            __threadfence();
            volatile double* vacc = accs;
            const float msw[5] = {0.0448f, 0.2856f, 0.3001f, 0.2363f, 0.1333f};
            const float npix[5] = {(float)HW, (float)(HW/4), (float)(HW/16),
                                   (float)(HW/64), (float)(HW/256)};
            float histc = 0.0f, lossc = 0.0f;
            if (t < 8) {
                int b = t;
                float l1 = (float)(vacc[80 + b] / (double)(3 * NBINS));
                float wgt = __builtin_amdgcn_exp2f((float)(b - B));   // 2^(b-8), exact
                histc = wgt * (l1 + 1.0f);
                float ms = 1.0f;
                #pragma unroll
                for (int l = 0; l < 4; ++l) {
                    float cs = (float)(vacc[40 + b * 5 + l] / (double)npix[l]);
                    ms *= fastpow((cs + 1.0f) * 0.5f, msw[l]);
                }
                float sm = (float)(vacc[b * 5 + 4] / (double)npix[4]);
                ms *= fastpow((sm + 1.0f) * 0.5f, msw[4]);
                lossc = 1.0f - ms;
            }
            #pragma unroll
            for (int o = 4; o >= 1; o >>= 1) {
                histc += __shfl_down(histc, o, 64);
                lossc += __shfl_down(lossc, o, 64);
            }
            if (t == 0) {
                float scaler = (float)HW / 20.0f;
                float hist_loss = histc / (float)B / scaler;
                float lab_l1 = (float)(vacc[88] / (double)((size_t)B * 3 * HW));
                out[0] = lab_l1 + hist_loss;
                out[1] = lossc / (float)B;
            }
        }
    }
}

extern "C" void kernel_launch(void* const* d_in, const int* in_sizes, int n_in,
                              void* d_out, int out_size, void* d_ws, size_t ws_size,
                              hipStream_t stream) {
    const float* pred = (const float*)d_in[1];
    const float* tgt  = (const float*)d_in[2];
    float* ws_f = (float*)d_ws;

    float* ppyr  = ws_f + OFF_PPYR;
    float* tpyr  = ws_f + OFF_TPYR;
    unsigned* histPart = (unsigned*)(ws_f + OFF_HISTPART);
    float* labPart = ws_f + OFF_LABPART;
    double* accs = (double*)(ws_f + OFF_ACC);
    float* out = (float*)d_out;

    // zero accumulators + completion counter (90 doubles)
    hipMemsetAsync(accs, 0, 90 * sizeof(double), stream);

    lab_ssim0_kernel<<<dim3(256, B), 256, 0, stream>>>(pred, tgt, histPart, labPart,
                                                       accs, ppyr, tpyr);

    tail_kernel<<<729, 256, 0, stream>>>(ppyr, tpyr, histPart, labPart, accs, out);
}